// Round 3
// baseline (220.857 us; speedup 1.0000x reference)
//
#include <hip/hip_runtime.h>
#include <hip/hip_fp16.h>
#include <math.h>

#define N 20000
#define F 128
#define C1 256   // HEADS*HIDDEN
#define HEADS 8
#define HID 32
#define NC 40
#define NCP 64   // padded h2h row stride (1 cache line)
#define NEG 0.2f

#define BSHIFT 7
#define NB 157        // buckets of 128 nodes
#define HBLOCKS 256
#define HM (NB * HBLOCKS)

#define PREPW_BLOCKS 16
#define W2PW_BLOCKS 6   // 24 frags * 64 lanes = 1536 half8 slots

typedef _Float16 half8 __attribute__((ext_vector_type(8)));
typedef float f32x4 __attribute__((ext_vector_type(4)));

__device__ __forceinline__ int edge_stride(const int* ei) {
    return (ei[1] == 0 && ei[3] == 0 && ei[5] == 0 && ei[7] == 0 && ei[9] == 0) ? 2 : 1;
}

__device__ __forceinline__ float lrelu(float v) { return v > 0.f ? v : NEG * v; }

// ---- K0: fused prep (W1 swizzle + W2 swizzle) + bucket histogram (LDS atomics only)
__global__ __launch_bounds__(256) void k_misc(
    const float* __restrict__ W1, _Float16* __restrict__ w1sw,
    const float* __restrict__ W2, _Float16* __restrict__ w2sw,
    const int* __restrict__ ei, int E, int* __restrict__ hist)
{
    const int b = blockIdx.x;
    const int tid = threadIdx.x;
    if (b < PREPW_BLOCKS) {
        const int slot = b * 256 + tid;
        const int lane = slot & 63;
        const int tile = slot >> 6;
        const int nt = tile & 15, ks = tile >> 4;
        const int n = nt * 16 + (lane & 15);
        const int k0 = ks * 32 + (lane >> 4) * 8;
        half8 tmp;
#pragma unroll
        for (int j = 0; j < 8; j++) tmp[j] = (_Float16)W1[(k0 + j) * C1 + n];
        *reinterpret_cast<half8*>(&w1sw[(size_t)slot * 8]) = tmp;
    } else if (b < PREPW_BLOCKS + W2PW_BLOCKS) {
        const int slot = (b - PREPW_BLOCKS) * 256 + tid;   // 0..1535
        const int lane = slot & 63;
        const int f = slot >> 6;          // 0..23
        const int nt = f % 3, ks = f / 3;
        const int n = nt * 16 + (lane & 15);
        const int k0 = ks * 32 + (lane >> 4) * 8;
        half8 tmp;
#pragma unroll
        for (int j = 0; j < 8; j++)
            tmp[j] = (n < NC) ? (_Float16)W2[(k0 + j) * NC + n] : (_Float16)0.f;
        *reinterpret_cast<half8*>(&w2sw[(size_t)slot * 8]) = tmp;
    } else {
        __shared__ int hcnt[NB];
        const int hb = b - PREPW_BLOCKS - W2PW_BLOCKS;
        if (tid < NB) hcnt[tid] = 0;
        __syncthreads();
        const int ET = E + N;
        const int per = (ET + HBLOCKS - 1) / HBLOCKS;
        const int lo = hb * per;
        const int hi = (lo + per < ET) ? (lo + per) : ET;
        const int st = edge_stride(ei);
        for (int i = lo + tid; i < hi; i += 256) {
            const int d = (i < E) ? ei[(size_t)st * (E + i)] : (i - E);
            atomicAdd(&hcnt[d >> BSHIFT], 1);
        }
        __syncthreads();
        if (tid < NB) hist[tid * HBLOCKS + hb] = hcnt[tid];
    }
}

// ---- K1: h1 = x @ W1 via MFMA (x read fp32, converted inline); fused projections.
__global__ __launch_bounds__(256) void k_gemm1_mfma(
    const float* __restrict__ x, const _Float16* __restrict__ w1sw,
    const float* __restrict__ a1s, const float* __restrict__ a1d,
    __half* __restrict__ h1h, float* __restrict__ as1, float* __restrict__ ad1)
{
    const int lane = threadIdx.x & 63;
    const int wid = (blockIdx.x * 256 + threadIdx.x) >> 6;
    const int m0 = wid * 16;
    const int g = lane >> 4, lm = lane & 15;
    const int arow = m0 + lm;
    half8 a[4];
    if (arow < N) {
        const float* xr = x + (size_t)arow * F;
#pragma unroll
        for (int ks = 0; ks < 4; ks++) {
            const float4 v0 = *reinterpret_cast<const float4*>(&xr[ks * 32 + g * 8]);
            const float4 v1 = *reinterpret_cast<const float4*>(&xr[ks * 32 + g * 8 + 4]);
            half8 t;
            t[0] = (_Float16)v0.x; t[1] = (_Float16)v0.y; t[2] = (_Float16)v0.z; t[3] = (_Float16)v0.w;
            t[4] = (_Float16)v1.x; t[5] = (_Float16)v1.y; t[6] = (_Float16)v1.z; t[7] = (_Float16)v1.w;
            a[ks] = t;
        }
    } else {
#pragma unroll
        for (int ks = 0; ks < 4; ks++) {
            half8 t;
#pragma unroll
            for (int j = 0; j < 8; j++) t[j] = (_Float16)0.f;
            a[ks] = t;
        }
    }
    const int rbase = m0 + g * 4;
    float ps[4] = {0.f, 0.f, 0.f, 0.f}, pd[4] = {0.f, 0.f, 0.f, 0.f};
#pragma unroll
    for (int nt = 0; nt < 16; nt++) {
        f32x4 acc = {0.f, 0.f, 0.f, 0.f};
#pragma unroll
        for (int ks = 0; ks < 4; ks++) {
            const half8 bfr = *reinterpret_cast<const half8*>(&w1sw[(size_t)((ks * 16 + nt) * 64 + lane) * 8]);
            acc = __builtin_amdgcn_mfma_f32_16x16x32_f16(a[ks], bfr, acc, 0, 0, 0);
        }
        const int col = nt * 16 + lm;
        const float av = a1s[col], dv = a1d[col];
#pragma unroll
        for (int r = 0; r < 4; r++) {
            const int row = rbase + r;
            if (row < N) h1h[(size_t)row * C1 + col] = __float2half((float)acc[r]);
            ps[r] = fmaf((float)acc[r], av, ps[r]);
            pd[r] = fmaf((float)acc[r], dv, pd[r]);
        }
        if (nt & 1) {
#pragma unroll
            for (int off = 1; off <= 8; off <<= 1) {
#pragma unroll
                for (int r = 0; r < 4; r++) {
                    ps[r] += __shfl_xor(ps[r], off);
                    pd[r] += __shfl_xor(pd[r], off);
                }
            }
            if (lm == 0) {
                const int head = nt >> 1;
#pragma unroll
                for (int r = 0; r < 4; r++) {
                    const int row = rbase + r;
                    if (row < N) {
                        as1[row * HEADS + head] = ps[r];
                        ad1[row * HEADS + head] = pd[r];
                    }
                }
            }
#pragma unroll
            for (int r = 0; r < 4; r++) { ps[r] = 0.f; pd[r] = 0.f; }
        }
    }
}

// ---- K2: per-bucket sums + exclusive scan of bucket sums. One block, 4 waves.
__global__ __launch_bounds__(256) void k_bss(const int* __restrict__ hist,
                                             int* __restrict__ bsum)
{
    __shared__ int bs[NB];
    __shared__ int wbase[4];
    const int t = threadIdx.x;
    const int lane = t & 63, wid = t >> 6;
    for (int b = wid; b < NB; b += 4) {
        const int* hp = &hist[b * HBLOCKS];
        int v = hp[lane] + hp[lane + 64] + hp[lane + 128] + hp[lane + 192];
#pragma unroll
        for (int off = 32; off >= 1; off >>= 1) v += __shfl_xor(v, off);
        if (lane == 0) bs[b] = v;
    }
    __syncthreads();
    const int vin = (t < NB) ? bs[t] : 0;
    int v = vin;
#pragma unroll
    for (int off = 1; off < 64; off <<= 1) {
        const int u = __shfl_up(v, off, 64);
        if (lane >= off) v += u;
    }
    if (lane == 63) wbase[wid] = v;
    __syncthreads();
    if (t < 64) {
        int w = (lane < 4) ? wbase[lane] : 0;
        const int orig = w;
#pragma unroll
        for (int off = 1; off < 4; off <<= 1) {
            const int u = __shfl_up(w, off, 64);
            if (lane >= off) w += u;
        }
        if (lane < 4) wbase[lane] = w - orig;
    }
    __syncthreads();
    if (t < NB) bsum[t] = wbase[wid] + v - vin;   // exclusive
}

// ---- K2c: per-bucket exclusive scan + bucket base -> hist in place.
__global__ __launch_bounds__(256) void k_hscan(int* __restrict__ hist,
                                               const int* __restrict__ bsum)
{
    __shared__ int wbase[4];
    const int b = blockIdx.x;
    const int tid = threadIdx.x;
    const int lane = tid & 63, wid = tid >> 6;
    const int vin = hist[b * HBLOCKS + tid];
    int v = vin;
#pragma unroll
    for (int off = 1; off < 64; off <<= 1) {
        const int u = __shfl_up(v, off, 64);
        if (lane >= off) v += u;
    }
    if (lane == 63) wbase[wid] = v;
    __syncthreads();
    if (tid < 64) {
        int w = (lane < 4) ? wbase[lane] : 0;
        const int orig = w;
#pragma unroll
        for (int off = 1; off < 4; off <<= 1) {
            const int u = __shfl_up(w, off, 64);
            if (lane >= off) w += u;
        }
        if (lane < 4) wbase[lane] = w - orig;
    }
    __syncthreads();
    hist[b * HBLOCKS + tid] = bsum[b] + wbase[wid] + v - vin;
}

// ---- K3: scatter edges into coarse buckets. LDS cursors only.
__global__ __launch_bounds__(256) void k_scatter(
    const int* __restrict__ ei, int E, const int* __restrict__ hist,
    int* __restrict__ buck)
{
    __shared__ int cur[NB];
    const int hb = blockIdx.x;
    const int tid = threadIdx.x;
    if (tid < NB) cur[tid] = hist[tid * HBLOCKS + hb];
    __syncthreads();
    const int ET = E + N;
    const int per = (ET + HBLOCKS - 1) / HBLOCKS;
    const int lo = hb * per;
    const int hi = (lo + per < ET) ? (lo + per) : ET;
    const int st = edge_stride(ei);
    for (int i = lo + tid; i < hi; i += 256) {
        int s, d;
        if (i < E) { s = ei[(size_t)st * i]; d = ei[(size_t)st * (E + i)]; }
        else       { s = i - E; d = i - E; }
        const int slot = atomicAdd(&cur[d >> BSHIFT], 1);
        buck[slot] = ((d & 127) << 16) | s;
    }
}

// ---- K4: per-bucket counting sort -> csr + rowptr.
__global__ __launch_bounds__(256) void k_bucket(
    const int* __restrict__ hist, const int* __restrict__ buck, int ET,
    int* __restrict__ csr, int* __restrict__ rowptr)
{
    __shared__ int cnt[128];
    __shared__ int pfx[128];
    const int b = blockIdx.x;
    const int tid = threadIdx.x;
    const int start = hist[b * HBLOCKS];
    const int end = (b == NB - 1) ? ET : hist[(b + 1) * HBLOCKS];
    if (tid < 128) cnt[tid] = 0;
    __syncthreads();
    for (int i = start + tid; i < end; i += 256)
        atomicAdd(&cnt[buck[i] >> 16], 1);
    __syncthreads();
    if (tid < 128) pfx[tid] = cnt[tid];
    __syncthreads();
    for (int off = 1; off < 128; off <<= 1) {
        int u = 0;
        if (tid < 128 && tid >= off) u = pfx[tid - off];
        __syncthreads();
        if (tid < 128) pfx[tid] += u;
        __syncthreads();
    }
    if (tid < 128) {
        const int node = b * 128 + tid;
        const int ebase = start + pfx[tid] - cnt[tid];
        if (node < N) rowptr[node] = ebase;
        cnt[tid] = ebase;
    }
    if (b == NB - 1 && tid == 0) rowptr[N] = ET;
    __syncthreads();
    for (int i = start + tid; i < end; i += 256) {
        const int val = buck[i];
        const int slot = atomicAdd(&cnt[val >> 16], 1);
        csr[slot] = val & 0xFFFF;
    }
}

// ---- K6: layer-1 aggregation, one WAVE per (node, head-quad). Wave-autonomous:
//      phase A: 4-lane-wide producers compute each (edge,head) weight ONCE into a
//      per-wave LDS strip (same-wave DS is in-order -> no barriers); zero-pad to 32.
//      phase B: scalarized csr (readfirstlane -> s_load/SALU addressing) + float4
//      LDS weight reads + gathers. No tail divergence, no shfl on critical path.
__global__ __launch_bounds__(256) void k_agg1(
    const int* __restrict__ rowptr, const int* __restrict__ csr,
    const __half* __restrict__ h1h,
    const float* __restrict__ as1, const float* __restrict__ ad1,
    const float* __restrict__ b1, __half* __restrict__ h1p)
{
    __shared__ float wlds[4][4][36];   // [wave][head'][edge] (+pad: 36 floats = 144B, 16B-aligned rows)
    const int tid = threadIdx.x;
    const int lane = tid & 63;
    const int wv = tid >> 6;
    const int gw = __builtin_amdgcn_readfirstlane(blockIdx.x * 4 + wv);
    const int n = gw >> 1;
    const int hq = gw & 1;                 // head quad: 0 -> heads 0-3 / ch 0-127, 1 -> heads 4-7
    const int hp = lane & 3;               // producer head-local
    const int ep = lane >> 2;              // producer edge slot (0..15)
    const int hcon = lane >> 4;            // consumer head-local
    const int head_p = hq * 4 + hp;
    const float dvp = ad1[n * HEADS + head_p];
    const int beg = rowptr[n], end = rowptr[n + 1];
    const int laneoff = hq * 256 + lane * 4;   // byte offset within a 512B h1h row
    float* wrow = wlds[wv][hp];
    const float* wcons = wlds[wv][hcon];
    const char* h1b = (const char*)h1h;
    float ax0 = 0.f, ay0 = 0.f, ax1 = 0.f, ay1 = 0.f, wsum = 0.f;
    for (int cs = beg; cs < end; cs += 32) {
        const int m = end - cs;
        // phase A: produce weights (w=0 padding for j >= m)
#pragma unroll
        for (int k = 0; k < 2; k++) {
            const int j = ep + 16 * k;
            float w = 0.f;
            if (j < m) {
                const int s = csr[cs + j];
                w = __expf(lrelu(as1[s * HEADS + head_p] + dvp));
            }
            wrow[j] = w;
            wsum += w;
        }
        // phase B: aggregate (csr reads are wave-uniform -> scalar loads)
        const int mm = (m < 32) ? m : 32;
        for (int j0 = 0; j0 < mm; j0 += 4) {
            const int o0 = (csr[cs + j0]     & 32767) << 9;
            const int o1 = (csr[cs + j0 + 1] & 32767) << 9;
            const int o2 = (csr[cs + j0 + 2] & 32767) << 9;
            const int o3 = (csr[cs + j0 + 3] & 32767) << 9;
            const float4 wf = *reinterpret_cast<const float4*>(&wcons[j0]);
            const float2 g0 = __half22float2(*(const __half2*)(h1b + (size_t)(unsigned)(o0 + laneoff)));
            const float2 g1 = __half22float2(*(const __half2*)(h1b + (size_t)(unsigned)(o1 + laneoff)));
            const float2 g2 = __half22float2(*(const __half2*)(h1b + (size_t)(unsigned)(o2 + laneoff)));
            const float2 g3 = __half22float2(*(const __half2*)(h1b + (size_t)(unsigned)(o3 + laneoff)));
            ax0 = fmaf(wf.x, g0.x, ax0); ay0 = fmaf(wf.x, g0.y, ay0);
            ax1 = fmaf(wf.y, g1.x, ax1); ay1 = fmaf(wf.y, g1.y, ay1);
            ax0 = fmaf(wf.z, g2.x, ax0); ay0 = fmaf(wf.z, g2.y, ay0);
            ax1 = fmaf(wf.w, g3.x, ax1); ay1 = fmaf(wf.w, g3.y, ay1);
        }
    }
    // denominator: reduce producer partials within each head class, then pick own head
#pragma unroll
    for (int off = 4; off < 64; off <<= 1) wsum += __shfl_xor(wsum, off);
    const float accw = __shfl(wsum, hcon, 64);
    const float inv = 1.f / accw;
    const int cb = hq * 128 + 2 * lane;
    float ox = (ax0 + ax1) * inv + b1[cb];
    float oy = (ay0 + ay1) * inv + b1[cb + 1];
    ox = (ox > 0.f) ? ox : (__expf(ox) - 1.f);
    oy = (oy > 0.f) ? oy : (__expf(oy) - 1.f);
    *reinterpret_cast<__half2*>(&h1p[(size_t)n * C1 + cb]) = __floats2half2_rn(ox, oy);
}

// ---- K7: h2 = h1p @ W2 via MFMA (NC=40 padded to 3x16 col tiles); fused as2/ad2.
//      h2h stored with row stride NCP=64 halves (128B = exactly one cache line).
__global__ __launch_bounds__(256) void k_gemm2_mfma(
    const __half* __restrict__ h1p, const _Float16* __restrict__ w2sw,
    const float* __restrict__ a2s, const float* __restrict__ a2d,
    __half* __restrict__ h2h, float* __restrict__ as2, float* __restrict__ ad2)
{
    const int lane = threadIdx.x & 63;
    const int wid = (blockIdx.x * 256 + threadIdx.x) >> 6;
    const int m0 = wid * 16;
    const int g = lane >> 4, lm = lane & 15;
    const int arow = m0 + lm;
    half8 a[8];
    if (arow < N) {
        const __half* hr = h1p + (size_t)arow * C1;
#pragma unroll
        for (int ks = 0; ks < 8; ks++)
            a[ks] = *reinterpret_cast<const half8*>(&hr[ks * 32 + g * 8]);
    } else {
#pragma unroll
        for (int ks = 0; ks < 8; ks++) {
            half8 t;
#pragma unroll
            for (int j = 0; j < 8; j++) t[j] = (_Float16)0.f;
            a[ks] = t;
        }
    }
    f32x4 acc[3];
#pragma unroll
    for (int nt = 0; nt < 3; nt++) acc[nt] = (f32x4){0.f, 0.f, 0.f, 0.f};
#pragma unroll
    for (int ks = 0; ks < 8; ks++) {
#pragma unroll
        for (int nt = 0; nt < 3; nt++) {
            const half8 bfr = *reinterpret_cast<const half8*>(&w2sw[(size_t)((ks * 3 + nt) * 64 + lane) * 8]);
            acc[nt] = __builtin_amdgcn_mfma_f32_16x16x32_f16(a[ks], bfr, acc[nt], 0, 0, 0);
        }
    }
    const int rbase = m0 + g * 4;
    float av[3], dvv[3];
#pragma unroll
    for (int nt = 0; nt < 3; nt++) {
        const int col = nt * 16 + lm;
        av[nt]  = (col < NC) ? a2s[col] : 0.f;
        dvv[nt] = (col < NC) ? a2d[col] : 0.f;
    }
#pragma unroll
    for (int r = 0; r < 4; r++) {
        const int row = rbase + r;
        float ps = 0.f, pd = 0.f;
#pragma unroll
        for (int nt = 0; nt < 3; nt++) {
            const float v = (float)acc[nt][r];
            const int col = nt * 16 + lm;
            if (row < N && col < NC) h2h[(size_t)row * NCP + col] = __float2half(v);
            ps = fmaf(v, av[nt], ps);
            pd = fmaf(v, dvv[nt], pd);
        }
#pragma unroll
        for (int off = 1; off <= 8; off <<= 1) {
            ps += __shfl_xor(ps, off);
            pd += __shfl_xor(pd, off);
        }
        if (lm == 0 && row < N) { as2[row] = ps; ad2[row] = pd; }
    }
}

// ---- K8: layer-2 aggregation + bias + log_softmax. One wave/node.
//      Scalarized: n/csr/as2 via readfirstlane -> s_load + SALU addressing.
__global__ __launch_bounds__(256) void k_agg2(
    const int* __restrict__ rowptr, const int* __restrict__ csr,
    const __half* __restrict__ h2h, const float* __restrict__ as2,
    const float* __restrict__ ad2, const float* __restrict__ b2,
    float* __restrict__ out)
{
    const int lane = threadIdx.x & 63;
    const int n = __builtin_amdgcn_readfirstlane((blockIdx.x * blockDim.x + threadIdx.x) >> 6);
    const int c = lane;
    const int cc = (c < NC) ? c : (NC - 1);
    const int lc2 = 2 * cc;
    const float adv = ad2[n];
    const int beg = rowptr[n], end = rowptr[n + 1];
    const char* h2b = (const char*)h2h;
    float acc0 = 0.f, acc1 = 0.f, accw = 0.f;
    int e = beg;
    for (; e + 3 < end; e += 4) {
        const int s0 = csr[e], s1 = csr[e + 1], s2 = csr[e + 2], s3 = csr[e + 3];
        const float w0 = __expf(lrelu(as2[s0] + adv));
        const float w1 = __expf(lrelu(as2[s1] + adv));
        const float w2 = __expf(lrelu(as2[s2] + adv));
        const float w3 = __expf(lrelu(as2[s3] + adv));
        const float g0 = __half2float(*(const __half*)(h2b + (unsigned)((s0 << 7) + lc2)));
        const float g1 = __half2float(*(const __half*)(h2b + (unsigned)((s1 << 7) + lc2)));
        const float g2 = __half2float(*(const __half*)(h2b + (unsigned)((s2 << 7) + lc2)));
        const float g3 = __half2float(*(const __half*)(h2b + (unsigned)((s3 << 7) + lc2)));
        accw += (w0 + w1) + (w2 + w3);
        acc0 = fmaf(w0, g0, acc0);
        acc1 = fmaf(w1, g1, acc1);
        acc0 = fmaf(w2, g2, acc0);
        acc1 = fmaf(w3, g3, acc1);
    }
    for (; e < end; e++) {
        const int s = csr[e];
        const float w = __expf(lrelu(as2[s] + adv));
        accw += w;
        acc0 = fmaf(w, __half2float(*(const __half*)(h2b + (unsigned)((s << 7) + lc2))), acc0);
    }
    const float v = (acc0 + acc1) / accw + b2[cc];
    float m = (c < NC) ? v : -1e30f;
#pragma unroll
    for (int off = 32; off >= 1; off >>= 1) m = fmaxf(m, __shfl_xor(m, off));
    float S = (c < NC) ? __expf(v - m) : 0.f;
#pragma unroll
    for (int off = 32; off >= 1; off >>= 1) S += __shfl_xor(S, off);
    if (c < NC) out[(size_t)n * NC + c] = v - m - logf(S);
}

extern "C" void kernel_launch(void* const* d_in, const int* in_sizes, int n_in,
                              void* d_out, int out_size, void* d_ws, size_t ws_size,
                              hipStream_t stream)
{
    const float* x   = (const float*)d_in[0];
    const int*   ei  = (const int*)d_in[1];
    const float* W1  = (const float*)d_in[2];
    const float* a1s = (const float*)d_in[3];
    const float* a1d = (const float*)d_in[4];
    const float* b1  = (const float*)d_in[5];
    const float* W2  = (const float*)d_in[6];
    const float* a2s = (const float*)d_in[7];
    const float* a2d = (const float*)d_in[8];
    const float* b2  = (const float*)d_in[9];
    float* out = (float*)d_out;

    const int E  = in_sizes[1] / 2;
    const int ET = E + N;

    auto align64 = [](size_t v) { return (v + 63) & ~(size_t)63; };
    char* ws = (char*)d_ws;
    size_t off = 0;
    _Float16* w1sw = (_Float16*)(ws + off); off = align64(off + (size_t)4096 * 8 * 2);
    _Float16* w2sw = (_Float16*)(ws + off); off = align64(off + (size_t)1536 * 8 * 2);
    __half* h1h = (__half*)(ws + off); off = align64(off + (size_t)N * C1 * 2);
    __half* h1p = (__half*)(ws + off); off = align64(off + (size_t)N * C1 * 2);
    __half* h2h = (__half*)(ws + off); off = align64(off + (size_t)N * NCP * 2);
    float* as1 = (float*)(ws + off); off = align64(off + (size_t)N * HEADS * 4);
    float* ad1 = (float*)(ws + off); off = align64(off + (size_t)N * HEADS * 4);
    float* as2 = (float*)(ws + off); off = align64(off + (size_t)N * 4);
    float* ad2 = (float*)(ws + off); off = align64(off + (size_t)N * 4);
    int* hist   = (int*)(ws + off); off = align64(off + (size_t)HM * 4);
    int* bsum   = (int*)(ws + off); off = align64(off + (size_t)NB * 4);
    int* buck   = (int*)(ws + off); off = align64(off + (size_t)ET * 4);
    int* rowptr = (int*)(ws + off); off = align64(off + (size_t)(N + 1) * 4);
    int* csr    = (int*)(ws + off); off = align64(off + (size_t)ET * 4 + 64);

    k_misc<<<PREPW_BLOCKS + W2PW_BLOCKS + HBLOCKS, 256, 0, stream>>>(W1, w1sw, W2, w2sw, ei, E, hist);
    k_gemm1_mfma<<<313, 256, 0, stream>>>(x, w1sw, a1s, a1d, h1h, as1, ad1);
    k_bss<<<1, 256, 0, stream>>>(hist, bsum);
    k_hscan<<<NB, 256, 0, stream>>>(hist, bsum);
    k_scatter<<<HBLOCKS, 256, 0, stream>>>(ei, E, hist, buck);
    k_bucket<<<NB, 256, 0, stream>>>(hist, buck, ET, csr, rowptr);
    k_agg1<<<N / 2, 256, 0, stream>>>(rowptr, csr, h1h, as1, ad1, b1, h1p);
    k_gemm2_mfma<<<313, 256, 0, stream>>>(h1p, w2sw, a2s, a2d, h2h, as2, ad2);
    k_agg2<<<5000, 256, 0, stream>>>(rowptr, csr, h2h, as2, ad2, b2, out);
}

// Round 4
// 209.643 us; speedup vs baseline: 1.0535x; 1.0535x over previous
//
#include <hip/hip_runtime.h>
#include <hip/hip_fp16.h>
#include <math.h>

#define N 20000
#define F 128
#define C1 256   // HEADS*HIDDEN
#define HEADS 8
#define HID 32
#define NC 40
#define NCP 64   // padded h2h row stride (1 cache line)
#define NEG 0.2f

#define BSHIFT 7
#define NB 157        // buckets of 128 nodes
#define HBLOCKS 256
#define HM (NB * HBLOCKS)

#define PREPW_BLOCKS 16
#define W2PW_BLOCKS 6   // 24 frags * 64 lanes = 1536 half8 slots

typedef _Float16 half8 __attribute__((ext_vector_type(8)));
typedef float f32x4 __attribute__((ext_vector_type(4)));

__device__ __forceinline__ int edge_stride(const int* ei) {
    return (ei[1] == 0 && ei[3] == 0 && ei[5] == 0 && ei[7] == 0 && ei[9] == 0) ? 2 : 1;
}

__device__ __forceinline__ float lrelu(float v) { return v > 0.f ? v : NEG * v; }

// ---- K0: fused prep (W1 swizzle + W2 swizzle) + bucket histogram (LDS atomics only)
__global__ __launch_bounds__(256) void k_misc(
    const float* __restrict__ W1, _Float16* __restrict__ w1sw,
    const float* __restrict__ W2, _Float16* __restrict__ w2sw,
    const int* __restrict__ ei, int E, int* __restrict__ hist)
{
    const int b = blockIdx.x;
    const int tid = threadIdx.x;
    if (b < PREPW_BLOCKS) {
        const int slot = b * 256 + tid;
        const int lane = slot & 63;
        const int tile = slot >> 6;
        const int nt = tile & 15, ks = tile >> 4;
        const int n = nt * 16 + (lane & 15);
        const int k0 = ks * 32 + (lane >> 4) * 8;
        half8 tmp;
#pragma unroll
        for (int j = 0; j < 8; j++) tmp[j] = (_Float16)W1[(k0 + j) * C1 + n];
        *reinterpret_cast<half8*>(&w1sw[(size_t)slot * 8]) = tmp;
    } else if (b < PREPW_BLOCKS + W2PW_BLOCKS) {
        const int slot = (b - PREPW_BLOCKS) * 256 + tid;   // 0..1535
        const int lane = slot & 63;
        const int f = slot >> 6;          // 0..23
        const int nt = f % 3, ks = f / 3;
        const int n = nt * 16 + (lane & 15);
        const int k0 = ks * 32 + (lane >> 4) * 8;
        half8 tmp;
#pragma unroll
        for (int j = 0; j < 8; j++)
            tmp[j] = (n < NC) ? (_Float16)W2[(k0 + j) * NC + n] : (_Float16)0.f;
        *reinterpret_cast<half8*>(&w2sw[(size_t)slot * 8]) = tmp;
    } else {
        __shared__ int hcnt[NB];
        const int hb = b - PREPW_BLOCKS - W2PW_BLOCKS;
        if (tid < NB) hcnt[tid] = 0;
        __syncthreads();
        const int ET = E + N;
        const int per = (ET + HBLOCKS - 1) / HBLOCKS;
        const int lo = hb * per;
        const int hi = (lo + per < ET) ? (lo + per) : ET;
        const int st = edge_stride(ei);
        for (int i = lo + tid; i < hi; i += 256) {
            const int d = (i < E) ? ei[(size_t)st * (E + i)] : (i - E);
            atomicAdd(&hcnt[d >> BSHIFT], 1);
        }
        __syncthreads();
        if (tid < NB) hist[tid * HBLOCKS + hb] = hcnt[tid];
    }
}

// ---- K1: h1 = x @ W1 via MFMA; h1 written as TWO channel planes (128 ch each)
//      so the edge-gather working set per XCD halves (planar + XCD steering).
__global__ __launch_bounds__(256) void k_gemm1_mfma(
    const float* __restrict__ x, const _Float16* __restrict__ w1sw,
    const float* __restrict__ a1s, const float* __restrict__ a1d,
    __half* __restrict__ h1hA, __half* __restrict__ h1hB,
    float* __restrict__ as1, float* __restrict__ ad1)
{
    const int lane = threadIdx.x & 63;
    const int wid = (blockIdx.x * 256 + threadIdx.x) >> 6;
    const int m0 = wid * 16;
    const int g = lane >> 4, lm = lane & 15;
    const int arow = m0 + lm;
    half8 a[4];
    if (arow < N) {
        const float* xr = x + (size_t)arow * F;
#pragma unroll
        for (int ks = 0; ks < 4; ks++) {
            const float4 v0 = *reinterpret_cast<const float4*>(&xr[ks * 32 + g * 8]);
            const float4 v1 = *reinterpret_cast<const float4*>(&xr[ks * 32 + g * 8 + 4]);
            half8 t;
            t[0] = (_Float16)v0.x; t[1] = (_Float16)v0.y; t[2] = (_Float16)v0.z; t[3] = (_Float16)v0.w;
            t[4] = (_Float16)v1.x; t[5] = (_Float16)v1.y; t[6] = (_Float16)v1.z; t[7] = (_Float16)v1.w;
            a[ks] = t;
        }
    } else {
#pragma unroll
        for (int ks = 0; ks < 4; ks++) {
            half8 t;
#pragma unroll
            for (int j = 0; j < 8; j++) t[j] = (_Float16)0.f;
            a[ks] = t;
        }
    }
    const int rbase = m0 + g * 4;
    float ps[4] = {0.f, 0.f, 0.f, 0.f}, pd[4] = {0.f, 0.f, 0.f, 0.f};
#pragma unroll
    for (int nt = 0; nt < 16; nt++) {
        f32x4 acc = {0.f, 0.f, 0.f, 0.f};
#pragma unroll
        for (int ks = 0; ks < 4; ks++) {
            const half8 bfr = *reinterpret_cast<const half8*>(&w1sw[(size_t)((ks * 16 + nt) * 64 + lane) * 8]);
            acc = __builtin_amdgcn_mfma_f32_16x16x32_f16(a[ks], bfr, acc, 0, 0, 0);
        }
        const int col = nt * 16 + lm;
        const float av = a1s[col], dv = a1d[col];
#pragma unroll
        for (int r = 0; r < 4; r++) {
            const int row = rbase + r;
            if (row < N) {
                if (nt < 8) h1hA[(size_t)row * 128 + col] = __float2half((float)acc[r]);
                else        h1hB[(size_t)row * 128 + (col - 128)] = __float2half((float)acc[r]);
            }
            ps[r] = fmaf((float)acc[r], av, ps[r]);
            pd[r] = fmaf((float)acc[r], dv, pd[r]);
        }
        if (nt & 1) {
#pragma unroll
            for (int off = 1; off <= 8; off <<= 1) {
#pragma unroll
                for (int r = 0; r < 4; r++) {
                    ps[r] += __shfl_xor(ps[r], off);
                    pd[r] += __shfl_xor(pd[r], off);
                }
            }
            if (lm == 0) {
                const int head = nt >> 1;
#pragma unroll
                for (int r = 0; r < 4; r++) {
                    const int row = rbase + r;
                    if (row < N) {
                        as1[row * HEADS + head] = ps[r];
                        ad1[row * HEADS + head] = pd[r];
                    }
                }
            }
#pragma unroll
            for (int r = 0; r < 4; r++) { ps[r] = 0.f; pd[r] = 0.f; }
        }
    }
}

// ---- K2: merged bucket-sum + global scan + per-bucket row scan (one kernel).
//      Every block redundantly computes all 157 bucket sums from L2-resident hist.
__global__ __launch_bounds__(256) void k_hscan2(int* __restrict__ hist)
{
    __shared__ int bs[160];
    __shared__ int wbase[4];
    __shared__ int base_s;
    const int b = blockIdx.x;
    const int tid = threadIdx.x;
    const int lane = tid & 63, wid = tid >> 6;
    // phase 1: all bucket sums (thread tid sums bucket tid's 256 counters)
    if (tid < NB) {
        const int4* hp = (const int4*)&hist[tid * HBLOCKS];
        int s = 0;
#pragma unroll 4
        for (int k = 0; k < 64; k++) { const int4 v = hp[k]; s += (v.x + v.y) + (v.z + v.w); }
        bs[tid] = s;
    }
    __syncthreads();
    // phase 2: exclusive scan of bs; keep entry b -> base_s
    {
        const int vin = (tid < NB) ? bs[tid] : 0;
        int v = vin;
#pragma unroll
        for (int off = 1; off < 64; off <<= 1) {
            const int u = __shfl_up(v, off, 64);
            if (lane >= off) v += u;
        }
        if (lane == 63) wbase[wid] = v;
        __syncthreads();
        if (tid < 64) {
            int w = (lane < 4) ? wbase[lane] : 0;
            const int orig = w;
#pragma unroll
            for (int off = 1; off < 4; off <<= 1) {
                const int u = __shfl_up(w, off, 64);
                if (lane >= off) w += u;
            }
            if (lane < 4) wbase[lane] = w - orig;
        }
        __syncthreads();
        if (tid == b) base_s = wbase[wid] + v - vin;   // exclusive global base of bucket b
    }
    __syncthreads();
    // phase 3: per-bucket row scan + add base
    const int vin2 = hist[b * HBLOCKS + tid];
    int v2 = vin2;
#pragma unroll
    for (int off = 1; off < 64; off <<= 1) {
        const int u = __shfl_up(v2, off, 64);
        if (lane >= off) v2 += u;
    }
    if (lane == 63) wbase[wid] = v2;
    __syncthreads();
    if (tid < 64) {
        int w = (lane < 4) ? wbase[lane] : 0;
        const int orig = w;
#pragma unroll
        for (int off = 1; off < 4; off <<= 1) {
            const int u = __shfl_up(w, off, 64);
            if (lane >= off) w += u;
        }
        if (lane < 4) wbase[lane] = w - orig;
    }
    __syncthreads();
    hist[b * HBLOCKS + tid] = base_s + wbase[wid] + v2 - vin2;
}

// ---- K3: scatter edges into coarse buckets. LDS cursors only.
__global__ __launch_bounds__(256) void k_scatter(
    const int* __restrict__ ei, int E, const int* __restrict__ hist,
    int* __restrict__ buck)
{
    __shared__ int cur[NB];
    const int hb = blockIdx.x;
    const int tid = threadIdx.x;
    if (tid < NB) cur[tid] = hist[tid * HBLOCKS + hb];
    __syncthreads();
    const int ET = E + N;
    const int per = (ET + HBLOCKS - 1) / HBLOCKS;
    const int lo = hb * per;
    const int hi = (lo + per < ET) ? (lo + per) : ET;
    const int st = edge_stride(ei);
    for (int i = lo + tid; i < hi; i += 256) {
        int s, d;
        if (i < E) { s = ei[(size_t)st * i]; d = ei[(size_t)st * (E + i)]; }
        else       { s = i - E; d = i - E; }
        const int slot = atomicAdd(&cur[d >> BSHIFT], 1);
        buck[slot] = ((d & 127) << 16) | s;
    }
}

// ---- K4: per-bucket counting sort -> csr + rowptr (+ zero sentinels past ET).
__global__ __launch_bounds__(256) void k_bucket(
    const int* __restrict__ hist, const int* __restrict__ buck, int ET,
    int* __restrict__ csr, int* __restrict__ rowptr)
{
    __shared__ int cnt[128];
    __shared__ int pfx[128];
    const int b = blockIdx.x;
    const int tid = threadIdx.x;
    const int start = hist[b * HBLOCKS];
    const int end = (b == NB - 1) ? ET : hist[(b + 1) * HBLOCKS];
    if (tid < 128) cnt[tid] = 0;
    __syncthreads();
    for (int i = start + tid; i < end; i += 256)
        atomicAdd(&cnt[buck[i] >> 16], 1);
    __syncthreads();
    if (tid < 128) pfx[tid] = cnt[tid];
    __syncthreads();
    for (int off = 1; off < 128; off <<= 1) {
        int u = 0;
        if (tid < 128 && tid >= off) u = pfx[tid - off];
        __syncthreads();
        if (tid < 128) pfx[tid] += u;
        __syncthreads();
    }
    if (tid < 128) {
        const int node = b * 128 + tid;
        const int ebase = start + pfx[tid] - cnt[tid];
        if (node < N) rowptr[node] = ebase;
        cnt[tid] = ebase;
    }
    if (b == NB - 1 && tid == 0) rowptr[N] = ET;
    if (b == NB - 1 && tid < 32) csr[ET + tid] = 0;   // sentinels: safe tail gathers
    __syncthreads();
    for (int i = start + tid; i < end; i += 256) {
        const int val = buck[i];
        const int slot = atomicAdd(&cnt[val >> 16], 1);
        csr[slot] = val & 0xFFFF;
    }
}

// ---- K6: layer-1 aggregation, one WAVE per (node, head-quad), PLANAR gather.
//      hq = blockIdx&1 -> even XCDs gather only plane A, odd only plane B
//      (round-robin block->XCD), halving each L2's gather working set.
__global__ __launch_bounds__(256) void k_agg1(
    const int* __restrict__ rowptr, const int* __restrict__ csr,
    const __half* __restrict__ h1hA, const __half* __restrict__ h1hB,
    const float* __restrict__ as1, const float* __restrict__ ad1,
    const float* __restrict__ b1, __half* __restrict__ h1p)
{
    __shared__ float wlds[4][4][36];   // [wave][head'][edge]
    const int tid = threadIdx.x;
    const int lane = tid & 63;
    const int wv = tid >> 6;
    const int hq = blockIdx.x & 1;             // head quad -> XCD parity
    const int n = (blockIdx.x >> 1) * 4 + wv;  // node (each parity covers all nodes)
    const int hp = lane & 3;                   // producer head-local
    const int ep = lane >> 2;                  // producer edge slot (0..15)
    const int hcon = lane >> 4;                // consumer head-local
    const int head_p = hq * 4 + hp;
    const float dvp = ad1[n * HEADS + head_p];
    const int beg = rowptr[n], end = rowptr[n + 1];
    const int laneoff = lane * 4;              // byte offset within 256B plane row
    float* wrow = wlds[wv][hp];
    const float* wcons = wlds[wv][hcon];
    const char* h1b = (const char*)(hq ? h1hB : h1hA);
    float ax0 = 0.f, ay0 = 0.f, ax1 = 0.f, ay1 = 0.f, wsum = 0.f;
    for (int cs = beg; cs < end; cs += 32) {
        const int m = end - cs;
        // phase A: produce weights (w=0 padding for j >= m)
#pragma unroll
        for (int k = 0; k < 2; k++) {
            const int j = ep + 16 * k;
            float w = 0.f;
            if (j < m) {
                const int s = csr[cs + j];
                w = __expf(lrelu(as1[s * HEADS + head_p] + dvp));
            }
            wrow[j] = w;
            wsum += w;
        }
        // phase B: aggregate (csr reads wave-uniform -> scalar loads; sentinels past ET)
        const int mm = (m < 32) ? m : 32;
        for (int j0 = 0; j0 < mm; j0 += 4) {
            const int o0 = (csr[cs + j0]     & 0xFFFF) << 8;
            const int o1 = (csr[cs + j0 + 1] & 0xFFFF) << 8;
            const int o2 = (csr[cs + j0 + 2] & 0xFFFF) << 8;
            const int o3 = (csr[cs + j0 + 3] & 0xFFFF) << 8;
            const float4 wf = *reinterpret_cast<const float4*>(&wcons[j0]);
            const float2 g0 = __half22float2(*(const __half2*)(h1b + (size_t)(unsigned)(o0 + laneoff)));
            const float2 g1 = __half22float2(*(const __half2*)(h1b + (size_t)(unsigned)(o1 + laneoff)));
            const float2 g2 = __half22float2(*(const __half2*)(h1b + (size_t)(unsigned)(o2 + laneoff)));
            const float2 g3 = __half22float2(*(const __half2*)(h1b + (size_t)(unsigned)(o3 + laneoff)));
            ax0 = fmaf(wf.x, g0.x, ax0); ay0 = fmaf(wf.x, g0.y, ay0);
            ax1 = fmaf(wf.y, g1.x, ax1); ay1 = fmaf(wf.y, g1.y, ay1);
            ax0 = fmaf(wf.z, g2.x, ax0); ay0 = fmaf(wf.z, g2.y, ay0);
            ax1 = fmaf(wf.w, g3.x, ax1); ay1 = fmaf(wf.w, g3.y, ay1);
        }
    }
    // denominator: reduce producer partials within each head class, pick own head
#pragma unroll
    for (int off = 4; off < 64; off <<= 1) wsum += __shfl_xor(wsum, off);
    const float accw = __shfl(wsum, hcon, 64);
    const float inv = 1.f / accw;
    const int cb = hq * 128 + 2 * lane;
    float ox = (ax0 + ax1) * inv + b1[cb];
    float oy = (ay0 + ay1) * inv + b1[cb + 1];
    ox = (ox > 0.f) ? ox : (__expf(ox) - 1.f);
    oy = (oy > 0.f) ? oy : (__expf(oy) - 1.f);
    *reinterpret_cast<__half2*>(&h1p[(size_t)n * C1 + cb]) = __floats2half2_rn(ox, oy);
}

// ---- K7: h2 = h1p @ W2 via MFMA (NC=40 padded to 3x16 col tiles); fused as2/ad2.
//      h2h stored with row stride NCP=64 halves (128B = exactly one cache line).
__global__ __launch_bounds__(256) void k_gemm2_mfma(
    const __half* __restrict__ h1p, const _Float16* __restrict__ w2sw,
    const float* __restrict__ a2s, const float* __restrict__ a2d,
    __half* __restrict__ h2h, float* __restrict__ as2, float* __restrict__ ad2)
{
    const int lane = threadIdx.x & 63;
    const int wid = (blockIdx.x * 256 + threadIdx.x) >> 6;
    const int m0 = wid * 16;
    const int g = lane >> 4, lm = lane & 15;
    const int arow = m0 + lm;
    half8 a[8];
    if (arow < N) {
        const __half* hr = h1p + (size_t)arow * C1;
#pragma unroll
        for (int ks = 0; ks < 8; ks++)
            a[ks] = *reinterpret_cast<const half8*>(&hr[ks * 32 + g * 8]);
    } else {
#pragma unroll
        for (int ks = 0; ks < 8; ks++) {
            half8 t;
#pragma unroll
            for (int j = 0; j < 8; j++) t[j] = (_Float16)0.f;
            a[ks] = t;
        }
    }
    f32x4 acc[3];
#pragma unroll
    for (int nt = 0; nt < 3; nt++) acc[nt] = (f32x4){0.f, 0.f, 0.f, 0.f};
#pragma unroll
    for (int ks = 0; ks < 8; ks++) {
#pragma unroll
        for (int nt = 0; nt < 3; nt++) {
            const half8 bfr = *reinterpret_cast<const half8*>(&w2sw[(size_t)((ks * 3 + nt) * 64 + lane) * 8]);
            acc[nt] = __builtin_amdgcn_mfma_f32_16x16x32_f16(a[ks], bfr, acc[nt], 0, 0, 0);
        }
    }
    const int rbase = m0 + g * 4;
    float av[3], dvv[3];
#pragma unroll
    for (int nt = 0; nt < 3; nt++) {
        const int col = nt * 16 + lm;
        av[nt]  = (col < NC) ? a2s[col] : 0.f;
        dvv[nt] = (col < NC) ? a2d[col] : 0.f;
    }
#pragma unroll
    for (int r = 0; r < 4; r++) {
        const int row = rbase + r;
        float ps = 0.f, pd = 0.f;
#pragma unroll
        for (int nt = 0; nt < 3; nt++) {
            const float v = (float)acc[nt][r];
            const int col = nt * 16 + lm;
            if (row < N && col < NC) h2h[(size_t)row * NCP + col] = __float2half(v);
            ps = fmaf(v, av[nt], ps);
            pd = fmaf(v, dvv[nt], pd);
        }
#pragma unroll
        for (int off = 1; off <= 8; off <<= 1) {
            ps += __shfl_xor(ps, off);
            pd += __shfl_xor(pd, off);
        }
        if (lm == 0 && row < N) { as2[row] = ps; ad2[row] = pd; }
    }
}

// ---- K8: layer-2 aggregation + bias + log_softmax. One wave/node, unroll 8.
//      h2h padded to one line/row and fully L2-resident (2.56 MB).
__global__ __launch_bounds__(256) void k_agg2(
    const int* __restrict__ rowptr, const int* __restrict__ csr,
    const __half* __restrict__ h2h, const float* __restrict__ as2,
    const float* __restrict__ ad2, const float* __restrict__ b2,
    float* __restrict__ out)
{
    const int lane = threadIdx.x & 63;
    const int n = (blockIdx.x * blockDim.x + threadIdx.x) >> 6;
    const int c = lane;
    const int cc = (c < NC) ? c : (NC - 1);
    const float adv = ad2[n];
    const int beg = rowptr[n], end = rowptr[n + 1];
    float acc = 0.f, accw = 0.f;
    int e = beg;
    for (; e + 7 < end; e += 8) {
        int s[8];
        float w[8], g[8];
#pragma unroll
        for (int j = 0; j < 8; j++) s[j] = csr[e + j];
#pragma unroll
        for (int j = 0; j < 8; j++) w[j] = __expf(lrelu(as2[s[j]] + adv));
#pragma unroll
        for (int j = 0; j < 8; j++) g[j] = __half2float(h2h[(size_t)s[j] * NCP + cc]);
#pragma unroll
        for (int j = 0; j < 8; j++) {
            accw += w[j];
            acc = fmaf(w[j], g[j], acc);
        }
    }
    for (; e + 3 < end; e += 4) {
        const int s0 = csr[e], s1 = csr[e + 1], s2 = csr[e + 2], s3 = csr[e + 3];
        const float w0 = __expf(lrelu(as2[s0] + adv));
        const float w1 = __expf(lrelu(as2[s1] + adv));
        const float w2 = __expf(lrelu(as2[s2] + adv));
        const float w3 = __expf(lrelu(as2[s3] + adv));
        const float g0 = __half2float(h2h[(size_t)s0 * NCP + cc]);
        const float g1 = __half2float(h2h[(size_t)s1 * NCP + cc]);
        const float g2 = __half2float(h2h[(size_t)s2 * NCP + cc]);
        const float g3 = __half2float(h2h[(size_t)s3 * NCP + cc]);
        accw += (w0 + w1) + (w2 + w3);
        acc = fmaf(w0, g0, acc);
        acc = fmaf(w1, g1, acc);
        acc = fmaf(w2, g2, acc);
        acc = fmaf(w3, g3, acc);
    }
    for (; e < end; e++) {
        const int s = csr[e];
        const float w = __expf(lrelu(as2[s] + adv));
        accw += w;
        acc = fmaf(w, __half2float(h2h[(size_t)s * NCP + cc]), acc);
    }
    const float v = acc / accw + b2[cc];
    float m = (c < NC) ? v : -1e30f;
#pragma unroll
    for (int off = 32; off >= 1; off >>= 1) m = fmaxf(m, __shfl_xor(m, off));
    float S = (c < NC) ? __expf(v - m) : 0.f;
#pragma unroll
    for (int off = 32; off >= 1; off >>= 1) S += __shfl_xor(S, off);
    if (c < NC) out[(size_t)n * NC + c] = v - m - logf(S);
}

extern "C" void kernel_launch(void* const* d_in, const int* in_sizes, int n_in,
                              void* d_out, int out_size, void* d_ws, size_t ws_size,
                              hipStream_t stream)
{
    const float* x   = (const float*)d_in[0];
    const int*   ei  = (const int*)d_in[1];
    const float* W1  = (const float*)d_in[2];
    const float* a1s = (const float*)d_in[3];
    const float* a1d = (const float*)d_in[4];
    const float* b1  = (const float*)d_in[5];
    const float* W2  = (const float*)d_in[6];
    const float* a2s = (const float*)d_in[7];
    const float* a2d = (const float*)d_in[8];
    const float* b2  = (const float*)d_in[9];
    float* out = (float*)d_out;

    const int E  = in_sizes[1] / 2;
    const int ET = E + N;

    auto align64 = [](size_t v) { return (v + 63) & ~(size_t)63; };
    char* ws = (char*)d_ws;
    size_t off = 0;
    _Float16* w1sw = (_Float16*)(ws + off); off = align64(off + (size_t)4096 * 8 * 2);
    _Float16* w2sw = (_Float16*)(ws + off); off = align64(off + (size_t)1536 * 8 * 2);
    __half* h1hA = (__half*)(ws + off); off = align64(off + (size_t)N * 128 * 2);
    __half* h1hB = (__half*)(ws + off); off = align64(off + (size_t)N * 128 * 2);
    __half* h1p = (__half*)(ws + off); off = align64(off + (size_t)N * C1 * 2);
    __half* h2h = (__half*)(ws + off); off = align64(off + (size_t)N * NCP * 2);
    float* as1 = (float*)(ws + off); off = align64(off + (size_t)N * HEADS * 4);
    float* ad1 = (float*)(ws + off); off = align64(off + (size_t)N * HEADS * 4);
    float* as2 = (float*)(ws + off); off = align64(off + (size_t)N * 4);
    float* ad2 = (float*)(ws + off); off = align64(off + (size_t)N * 4);
    int* hist   = (int*)(ws + off); off = align64(off + (size_t)HM * 4);
    int* buck   = (int*)(ws + off); off = align64(off + (size_t)ET * 4);
    int* rowptr = (int*)(ws + off); off = align64(off + (size_t)(N + 1) * 4);
    int* csr    = (int*)(ws + off); off = align64(off + (size_t)ET * 4 + 128);

    k_misc<<<PREPW_BLOCKS + W2PW_BLOCKS + HBLOCKS, 256, 0, stream>>>(W1, w1sw, W2, w2sw, ei, E, hist);
    k_gemm1_mfma<<<313, 256, 0, stream>>>(x, w1sw, a1s, a1d, h1hA, h1hB, as1, ad1);
    k_hscan2<<<NB, 256, 0, stream>>>(hist);
    k_scatter<<<HBLOCKS, 256, 0, stream>>>(ei, E, hist, buck);
    k_bucket<<<NB, 256, 0, stream>>>(hist, buck, ET, csr, rowptr);
    k_agg1<<<N / 2, 256, 0, stream>>>(rowptr, csr, h1hA, h1hB, as1, ad1, b1, h1p);
    k_gemm2_mfma<<<313, 256, 0, stream>>>(h1p, w2sw, a2s, a2d, h2h, as2, ad2);
    k_agg2<<<5000, 256, 0, stream>>>(rowptr, csr, h2h, as2, ad2, b2, out);
}